// Round 4
// baseline (1451.544 us; speedup 1.0000x reference)
//
#include <hip/hip_runtime.h>

typedef __attribute__((ext_vector_type(4))) float f32x4;
typedef __attribute__((ext_vector_type(8))) short bf16x8;
typedef __attribute__((ext_vector_type(4))) unsigned int u32x4;

static __device__ __forceinline__ unsigned short f2bf(float f) {
  union { float f; unsigned int u; } v;
  v.f = f;
  unsigned int r = v.u + 0x7fffu + ((v.u >> 16) & 1u);  // RNE
  return (unsigned short)(r >> 16);
}
static __device__ __forceinline__ unsigned packbf(float a, float b) {
  return (unsigned)f2bf(a) | ((unsigned)f2bf(b) << 16);
}
static __device__ __forceinline__ void gload16(const void* g, void* l) {
  __builtin_amdgcn_global_load_lds(
      (const __attribute__((address_space(1))) unsigned int*)g,
      (__attribute__((address_space(3))) unsigned int*)l, 16, 0, 0);
}

// ---------------------------------------------------------------------------
// LSQ 4-bit fake-quant + pack to fragment-linear bf16.
// lane l holds wq[n][k], n = cf*16 + (l&15), k = ks*32 + (l>>4)*8 + j.
// w1 addr: ((cf*8 + ks)*64 + l)*8   (cf-major)
// w2 addr: ((ks*16 + cf)*64 + l)*8  (ks-major)
// ---------------------------------------------------------------------------
__global__ void lsq_pack(const float* __restrict__ w1, const float* __restrict__ a1,
                         const float* __restrict__ w2, const float* __restrict__ a2,
                         unsigned short* __restrict__ pq)
{
  int g = blockIdx.x * 256 + threadIdx.x;     // 0..16383
  int gg = g & 8191;
  const float* w = (g < 8192) ? w1 : w2;
  float alpha = (g < 8192) ? *a1 : *a2;
  unsigned short* dst = pq + ((g < 8192) ? 0 : 65536);
  int l  = gg & 63;
  int ks = (gg >> 6) & 7;
  int cf = gg >> 9;
  int n  = cf * 16 + (l & 15);
  int kb = ks * 32 + (l >> 4) * 8;
  const float* src = w + n * 256 + kb;
  unsigned short e[8];
  #pragma unroll
  for (int j = 0; j < 8; ++j) {
    float q = src[j] / alpha;
    q = fminf(fmaxf(q, -8.f), 7.f);
    q = rintf(q) * alpha;                     // round-half-even == jnp.round
    e[j] = f2bf(q);
  }
  uint4 o;
  o.x = e[0] | ((unsigned)e[1] << 16);
  o.y = e[2] | ((unsigned)e[3] << 16);
  o.z = e[4] | ((unsigned)e[5] << 16);
  o.w = e[6] | ((unsigned)e[7] << 16);
  int di = (g < 8192) ? ((cf * 8 + ks) * 64 + l) : ((ks * 16 + cf) * 64 + l);
  *(uint4*)(dst + di * 8) = o;
}

// ---------------------------------------------------------------------------
// Fused: out = sigmoid(relu(x@wq1^T + b1) @ wq2^T + b2)
// 512 thr (8 waves), wave-tile 16 rows, block-tile 128 rows.
// w1 (128KB) + biases staged in LDS ONCE; w2 frags read per-use from L2;
// x in registers (split-half prefetch of next tile under current compute);
// h transposed in-register via ds_bpermute. ZERO barriers after prologue —
// waves are fully independent streams.
// ---------------------------------------------------------------------------
__global__ __launch_bounds__(512, 2) void lsq_fused(
    const float* __restrict__ x, const unsigned short* __restrict__ pqw,
    const float* __restrict__ b1, const float* __restrict__ b2,
    float* __restrict__ out, int ntiles)
{
  __shared__ __align__(16) char lds[131072 + 2048];
  char* const blds1 = lds + 131072;
  char* const blds2 = lds + 132096;

  const int tid  = threadIdx.x;
  const int lane = tid & 63;
  const int w    = tid >> 6;
  const int l15  = lane & 15;
  const int l4   = lane >> 4;
  const char* pq2 = (const char*)pqw + 131072;
  const int G = gridDim.x;
  const f32x4 fz = {0.f, 0.f, 0.f, 0.f};

  // bpermute gather indices (verified layout, R2/R3 pass): byte addr = lane*4
  int idx[4];
  #pragma unroll
  for (int wi = 0; wi < 4; ++wi)
    idx[wi] = (((l4 & 1) * 2 + (wi >> 1)) * 16 + l15) * 4;

  // ---- prologue: stage w1 (128KB) + biases into LDS; issue first x tile ----
  #pragma unroll
  for (int it = 0; it < 16; ++it) {
    const int chunk = it * 8 + w;            // 0..127 x 1KB
    gload16((const char*)pqw + chunk * 1024 + lane * 16, lds + chunk * 1024);
  }
  if (w == 0) gload16((const char*)b1 + lane * 16, blds1);
  if (w == 1) gload16((const char*)b2 + lane * 16, blds2);

  int t = blockIdx.x;
  f32x4 raw[16];
  {
    const float* xp = x + ((size_t)t * 128 + w * 16 + l15) * 256;
    #pragma unroll
    for (int ks = 0; ks < 8; ++ks) {
      raw[2 * ks]     = *(const f32x4*)(xp + ks * 32 + l4 * 8);
      raw[2 * ks + 1] = *(const f32x4*)(xp + ks * 32 + l4 * 8 + 4);
    }
  }
  __syncthreads();   // the ONLY barrier: w1/bias LDS visible to all waves

  for (;;) {
    // convert raw fp32 -> bf16 B-fragments
    bf16x8 xf[8];
    #pragma unroll
    for (int ks = 0; ks < 8; ++ks) {
      bf16x8 b;
      #pragma unroll
      for (int j = 0; j < 4; ++j) {
        b[j]     = (short)f2bf(raw[2 * ks][j]);
        b[j + 4] = (short)f2bf(raw[2 * ks + 1][j]);
      }
      xf[ks] = b;
    }

    const int tn = t + G;
    const bool more = tn < ntiles;
    const float* xq = x + ((size_t)tn * 128 + w * 16 + l15) * 256;
    if (more) {                               // prefetch half 0 (ks 0..3)
      #pragma unroll
      for (int ks = 0; ks < 4; ++ks) {
        raw[2 * ks]     = *(const f32x4*)(xq + ks * 32 + l4 * 8);
        raw[2 * ks + 1] = *(const f32x4*)(xq + ks * 32 + l4 * 8 + 4);
      }
    }

    f32x4 acc2[16];
    #pragma unroll
    for (int c2 = 0; c2 < 16; ++c2) acc2[c2] = fz;

    #pragma unroll
    for (int r = 0; r < 8; ++r) {
      // issue w2 frags early (L2-hot; latency hides under layer-1 MFMA)
      bf16x8 w2f[16];
      #pragma unroll
      for (int c2 = 0; c2 < 8; ++c2)
        w2f[c2] = *(const bf16x8*)(pq2 + (r * 16 + c2) * 1024 + lane * 16);

      // layer-1: cf pair {2r, 2r+1} from LDS-resident w1
      f32x4 a0 = fz, a1 = fz;
      #pragma unroll
      for (int ks = 0; ks < 8; ++ks) {
        bf16x8 wfA = *(const bf16x8*)(lds + ((2 * r)     * 8 + ks) * 1024 + lane * 16);
        bf16x8 wfB = *(const bf16x8*)(lds + ((2 * r + 1) * 8 + ks) * 1024 + lane * 16);
        a0 = __builtin_amdgcn_mfma_f32_16x16x32_bf16(wfA, xf[ks], a0, 0, 0, 0);
        a1 = __builtin_amdgcn_mfma_f32_16x16x32_bf16(wfB, xf[ks], a1, 0, 0, 0);
      }
      #pragma unroll
      for (int c2 = 8; c2 < 16; ++c2)
        w2f[c2] = *(const bf16x8*)(pq2 + (r * 16 + c2) * 1024 + lane * 16);

      if (r == 4 && more) {                   // prefetch half 1 (ks 4..7)
        #pragma unroll
        for (int ks = 4; ks < 8; ++ks) {
          raw[2 * ks]     = *(const f32x4*)(xq + ks * 32 + l4 * 8);
          raw[2 * ks + 1] = *(const f32x4*)(xq + ks * 32 + l4 * 8 + 4);
        }
      }

      // bias + relu + pack + in-register C-layout -> B-frag transpose
      f32x4 bv0 = *(const f32x4*)(blds1 + r * 128 + l4 * 16);
      f32x4 bv1 = *(const f32x4*)(blds1 + r * 128 + 64 + l4 * 16);
      f32x4 v0, v1;
      #pragma unroll
      for (int j = 0; j < 4; ++j) {
        v0[j] = fmaxf(a0[j] + bv0[j], 0.f);
        v1[j] = fmaxf(a1[j] + bv1[j], 0.f);
      }
      const unsigned D0 = packbf(v0[0], v0[1]);
      const unsigned D1 = packbf(v0[2], v0[3]);
      const unsigned D2 = packbf(v1[0], v1[1]);
      const unsigned D3 = packbf(v1[2], v1[3]);
      unsigned hd[4];
      #pragma unroll
      for (int wi = 0; wi < 4; ++wi) {
        const int p0 = __builtin_amdgcn_ds_bpermute(idx[wi], (int)((wi & 1) ? D1 : D0));
        const int p1 = __builtin_amdgcn_ds_bpermute(idx[wi], (int)((wi & 1) ? D3 : D2));
        hd[wi] = (l4 >= 2) ? (unsigned)p1 : (unsigned)p0;
      }
      union { u32x4 u; bf16x8 v; } cv;
      cv.u[0] = hd[0]; cv.u[1] = hd[1]; cv.u[2] = hd[2]; cv.u[3] = hd[3];
      const bf16x8 hf = cv.v;

      // layer-2 partial, ks2 = r
      #pragma unroll
      for (int c2 = 0; c2 < 16; ++c2)
        acc2[c2] = __builtin_amdgcn_mfma_f32_16x16x32_bf16(w2f[c2], hf, acc2[c2], 0, 0, 0);
    }

    // epilogue: bias2 + sigmoid + store
    {
      float* op = out + ((size_t)t * 128 + w * 16 + l15) * 256 + l4 * 4;
      #pragma unroll
      for (int c2 = 0; c2 < 16; ++c2) {
        f32x4 bb = *(const f32x4*)(blds2 + c2 * 64 + l4 * 16);
        f32x4 o;
        #pragma unroll
        for (int j = 0; j < 4; ++j) {
          const float z = acc2[c2][j] + bb[j];
          o[j] = 1.f / (1.f + __expf(-z));
        }
        *(f32x4*)(op + c2 * 16) = o;
      }
    }
    if (!more) break;
    t = tn;
  }
}

// ---------------------------------------------------------------------------
extern "C" void kernel_launch(void* const* d_in, const int* in_sizes, int n_in,
                              void* d_out, int out_size, void* d_ws, size_t ws_size,
                              hipStream_t stream)
{
  const float* x  = (const float*)d_in[0];
  const float* w1 = (const float*)d_in[1];
  const float* b1 = (const float*)d_in[2];
  const float* a1 = (const float*)d_in[3];
  const float* w2 = (const float*)d_in[4];
  const float* b2 = (const float*)d_in[5];
  const float* a2 = (const float*)d_in[6];
  float* out = (float*)d_out;
  (void)ws_size;

  unsigned short* pq = (unsigned short*)d_ws;   // 256 KB packed weights

  long long totalRows = (long long)in_sizes[0] / 256;
  int ntiles = (int)(totalRows / 128);          // 2048 at N=262144

  lsq_pack<<<64, 256, 0, stream>>>(w1, a1, w2, a2, pq);

  int grid = ntiles < 256 ? ntiles : 256;
  lsq_fused<<<grid, 512, 0, stream>>>(x, pq, b1, b2, out, ntiles);
}

// Round 5
// 415.983 us; speedup vs baseline: 3.4894x; 3.4894x over previous
//
#include <hip/hip_runtime.h>

typedef __attribute__((ext_vector_type(4))) float f32x4;
typedef __attribute__((ext_vector_type(8))) short bf16x8;
typedef __attribute__((ext_vector_type(4))) unsigned int u32x4;

static __device__ __forceinline__ unsigned short f2bf(float f) {
  union { float f; unsigned int u; } v;
  v.f = f;
  unsigned int r = v.u + 0x7fffu + ((v.u >> 16) & 1u);  // RNE
  return (unsigned short)(r >> 16);
}
static __device__ __forceinline__ unsigned packbf(float a, float b) {
  return (unsigned)f2bf(a) | ((unsigned)f2bf(b) << 16);
}
static __device__ __forceinline__ void gload16(const void* g, void* l) {
  __builtin_amdgcn_global_load_lds(
      (const __attribute__((address_space(1))) unsigned int*)g,
      (__attribute__((address_space(3))) unsigned int*)l, 16, 0, 0);
}

// ---------------------------------------------------------------------------
// LSQ 4-bit fake-quant + pack to fragment-linear bf16.
// lane l holds wq[n][k], n = cf*16 + (l&15), k = ks*32 + (l>>4)*8 + j.
// w1 addr: ((cf*8 + ks)*64 + l)*8   (cf-major -> 16KB cf-pair chunks)
// w2 addr: ((ks*16 + cf)*64 + l)*8  (ks-major -> 16KB ks-slice chunks)
// ---------------------------------------------------------------------------
__global__ void lsq_pack(const float* __restrict__ w1, const float* __restrict__ a1,
                         const float* __restrict__ w2, const float* __restrict__ a2,
                         unsigned short* __restrict__ pq)
{
  int g = blockIdx.x * 256 + threadIdx.x;     // 0..16383
  int gg = g & 8191;
  const float* w = (g < 8192) ? w1 : w2;
  float alpha = (g < 8192) ? *a1 : *a2;
  unsigned short* dst = pq + ((g < 8192) ? 0 : 65536);
  int l  = gg & 63;
  int ks = (gg >> 6) & 7;
  int cf = gg >> 9;
  int n  = cf * 16 + (l & 15);
  int kb = ks * 32 + (l >> 4) * 8;
  const float* src = w + n * 256 + kb;
  unsigned short e[8];
  #pragma unroll
  for (int j = 0; j < 8; ++j) {
    float q = src[j] / alpha;
    q = fminf(fmaxf(q, -8.f), 7.f);
    q = rintf(q) * alpha;                     // round-half-even == jnp.round
    e[j] = f2bf(q);
  }
  uint4 o;
  o.x = e[0] | ((unsigned)e[1] << 16);
  o.y = e[2] | ((unsigned)e[3] << 16);
  o.z = e[4] | ((unsigned)e[5] << 16);
  o.w = e[6] | ((unsigned)e[7] << 16);
  int di = (g < 8192) ? ((cf * 8 + ks) * 64 + l) : ((ks * 16 + cf) * 64 + l);
  *(uint4*)(dst + di * 8) = o;
}

// ---------------------------------------------------------------------------
// Fused: out = sigmoid(relu(x@wq1^T + b1) @ wq2^T + b2)
// 256 thr (4 waves), wave-tile 32 rows (2 groups of 16), block-tile 128 rows.
// LDS 68KB/block -> 2 independent blocks/CU (cross-block latency hiding);
// __launch_bounds__(256,2) -> 256-reg budget (acc in AGPRs, no spill).
// Weights double-buffered in LDS via global_load_lds, one chunk-pair/round,
// one __syncthreads per round (R2's proven scheme). h transposed C-layout ->
// B-frag fully in-register via ds_bpermute (no h LDS, no bank conflicts).
// ---------------------------------------------------------------------------
__global__ __launch_bounds__(256, 2) void lsq_fused(
    const float* __restrict__ x, const unsigned short* __restrict__ pqw,
    const float* __restrict__ b1, const float* __restrict__ b2,
    float* __restrict__ out, int ntiles)
{
  __shared__ __align__(16) char w1lds[2][16384];
  __shared__ __align__(16) char w2lds[2][16384];
  __shared__ __align__(16) char blds1[1024];
  __shared__ __align__(16) char blds2[1024];

  const int tid  = threadIdx.x;
  const int lane = tid & 63;
  const int w    = tid >> 6;          // 0..3
  const int l15  = lane & 15;
  const int l4   = lane >> 4;
  const char* pq1 = (const char*)pqw;
  const char* pq2 = (const char*)pqw + 131072;
  const int G = gridDim.x;
  const f32x4 fz = {0.f, 0.f, 0.f, 0.f};

  // bpermute gather indices (verified R3/R4): byte addr = src_lane*4,
  // src lane = ((l4&1)*2 + (wi>>1))*16 + l15
  int idx[4];
  #pragma unroll
  for (int wi = 0; wi < 4; ++wi)
    idx[wi] = (((l4 & 1) * 2 + (wi >> 1)) * 16 + l15) * 4;

  // ---- prologue: stage round-0 weight chunks + biases ----
  #pragma unroll
  for (int i = 0; i < 4; ++i) {
    const int sub = i * 4 + w;
    gload16(pq1 + sub * 1024 + lane * 16, &w1lds[0][0] + sub * 1024);
    gload16(pq2 + sub * 1024 + lane * 16, &w2lds[0][0] + sub * 1024);
  }
  if (w == 0) gload16((const char*)b1 + lane * 16, blds1);
  if (w == 1) gload16((const char*)b2 + lane * 16, blds2);
  __syncthreads();

  for (int t = blockIdx.x; t < ntiles; t += G) {
    // ---- load + convert x for this tile (per-wave, no sync) ----
    bf16x8 xf[2][8];
    #pragma unroll
    for (int g = 0; g < 2; ++g) {
      const float* xp = x + ((size_t)t * 128 + w * 32 + g * 16 + l15) * 256 + l4 * 8;
      #pragma unroll
      for (int ks = 0; ks < 8; ++ks) {
        f32x4 r0 = *(const f32x4*)(xp + ks * 32);
        f32x4 r1 = *(const f32x4*)(xp + ks * 32 + 4);
        bf16x8 b;
        #pragma unroll
        for (int j = 0; j < 4; ++j) {
          b[j]     = (short)f2bf(r0[j]);
          b[j + 4] = (short)f2bf(r1[j]);
        }
        xf[g][ks] = b;
      }
    }

    f32x4 acc2[2][16];
    #pragma unroll
    for (int g = 0; g < 2; ++g)
      #pragma unroll
      for (int c2 = 0; c2 < 16; ++c2) acc2[g][c2] = fz;

    #pragma unroll
    for (int r = 0; r < 8; ++r) {
      const int cur = r & 1;
      const int nxt = cur ^ 1;
      const int rn  = (r + 1) & 7;
      // stage next round's chunk pair (retired readers: previous round's barrier)
      #pragma unroll
      for (int i = 0; i < 4; ++i) {
        const int sub = i * 4 + w;
        gload16(pq1 + rn * 16384 + sub * 1024 + lane * 16, &w1lds[nxt][0] + sub * 1024);
        gload16(pq2 + rn * 16384 + sub * 1024 + lane * 16, &w2lds[nxt][0] + sub * 1024);
      }

      // ---- layer-1: cf pair {2r, 2r+1} ----
      f32x4 aA[2][2] = {{fz, fz}, {fz, fz}};
      #pragma unroll
      for (int c = 0; c < 2; ++c)
        #pragma unroll
        for (int ks = 0; ks < 8; ++ks) {
          bf16x8 wf = *(const bf16x8*)(&w1lds[cur][0] + c * 8192 + ks * 1024 + lane * 16);
          aA[c][0] = __builtin_amdgcn_mfma_f32_16x16x32_bf16(wf, xf[0][ks], aA[c][0], 0, 0, 0);
          aA[c][1] = __builtin_amdgcn_mfma_f32_16x16x32_bf16(wf, xf[1][ks], aA[c][1], 0, 0, 0);
        }

      // ---- bias + relu + pack + in-register transpose -> hf[g] ----
      f32x4 bv0 = *(const f32x4*)(blds1 + r * 128 + l4 * 16);
      f32x4 bv1 = *(const f32x4*)(blds1 + r * 128 + 64 + l4 * 16);
      bf16x8 hf[2];
      #pragma unroll
      for (int g = 0; g < 2; ++g) {
        f32x4 v0, v1;
        #pragma unroll
        for (int j = 0; j < 4; ++j) {
          v0[j] = fmaxf(aA[0][g][j] + bv0[j], 0.f);
          v1[j] = fmaxf(aA[1][g][j] + bv1[j], 0.f);
        }
        const unsigned D0 = packbf(v0[0], v0[1]);
        const unsigned D1 = packbf(v0[2], v0[3]);
        const unsigned D2 = packbf(v1[0], v1[1]);
        const unsigned D3 = packbf(v1[2], v1[3]);
        unsigned hd[4];
        #pragma unroll
        for (int wi = 0; wi < 4; ++wi) {
          const int p0 = __builtin_amdgcn_ds_bpermute(idx[wi], (int)((wi & 1) ? D1 : D0));
          const int p1 = __builtin_amdgcn_ds_bpermute(idx[wi], (int)((wi & 1) ? D3 : D2));
          hd[wi] = (l4 >= 2) ? (unsigned)p1 : (unsigned)p0;
        }
        union { u32x4 u; bf16x8 v; } cv;
        cv.u[0] = hd[0]; cv.u[1] = hd[1]; cv.u[2] = hd[2]; cv.u[3] = hd[3];
        hf[g] = cv.v;
      }

      // ---- layer-2 partial, ks2 = r ----
      #pragma unroll
      for (int c2 = 0; c2 < 16; ++c2) {
        bf16x8 wf2 = *(const bf16x8*)(&w2lds[cur][0] + c2 * 1024 + lane * 16);
        acc2[0][c2] = __builtin_amdgcn_mfma_f32_16x16x32_bf16(wf2, hf[0], acc2[0][c2], 0, 0, 0);
        acc2[1][c2] = __builtin_amdgcn_mfma_f32_16x16x32_bf16(wf2, hf[1], acc2[1][c2], 0, 0, 0);
      }
      __syncthreads();   // drains staging DMA; retires all readers of cur
    }

    // ---- epilogue: bias2 + sigmoid + store ----
    #pragma unroll
    for (int g = 0; g < 2; ++g) {
      float* op = out + ((size_t)t * 128 + w * 32 + g * 16 + l15) * 256 + l4 * 4;
      #pragma unroll
      for (int c2 = 0; c2 < 16; ++c2) {
        f32x4 bb = *(const f32x4*)(blds2 + c2 * 64 + l4 * 16);
        f32x4 o;
        #pragma unroll
        for (int j = 0; j < 4; ++j) {
          const float z = acc2[g][c2][j] + bb[j];
          o[j] = 1.f / (1.f + __expf(-z));
        }
        *(f32x4*)(op + c2 * 16) = o;
      }
    }
  }
}

// ---------------------------------------------------------------------------
extern "C" void kernel_launch(void* const* d_in, const int* in_sizes, int n_in,
                              void* d_out, int out_size, void* d_ws, size_t ws_size,
                              hipStream_t stream)
{
  const float* x  = (const float*)d_in[0];
  const float* w1 = (const float*)d_in[1];
  const float* b1 = (const float*)d_in[2];
  const float* a1 = (const float*)d_in[3];
  const float* w2 = (const float*)d_in[4];
  const float* b2 = (const float*)d_in[5];
  const float* a2 = (const float*)d_in[6];
  float* out = (float*)d_out;
  (void)ws_size;

  unsigned short* pq = (unsigned short*)d_ws;   // 256 KB packed weights

  long long totalRows = (long long)in_sizes[0] / 256;
  int ntiles = (int)(totalRows / 128);          // 2048 at N=262144

  lsq_pack<<<64, 256, 0, stream>>>(w1, a1, w2, a2, pq);

  int grid = ntiles < 512 ? ntiles : 512;       // 2 blocks per CU
  lsq_fused<<<grid, 256, 0, stream>>>(x, pq, b1, b2, out, ntiles);
}